// Round 9
// baseline (311.736 us; speedup 1.0000x reference)
//
#include <hip/hip_runtime.h>

#define NB     8192
#define SEQ    180
#define SB     72     // bf16 LDS row stride: 144 B, 16B-aligned rows
#define XSP    96     // xs row stride (floats), 384 B, 16B-aligned

typedef __bf16 bf16x8 __attribute__((ext_vector_type(8)));
typedef float  f32x4  __attribute__((ext_vector_type(4)));

#define L2E 1.44269504088896340736f
#define MFMA __builtin_amdgcn_mfma_f32_16x16x32_bf16

__device__ __forceinline__ float tanh_f(float x) {
    float e = __builtin_amdgcn_exp2f((2.0f * L2E) * x);
    return 1.0f - 2.0f * __builtin_amdgcn_rcpf(1.0f + e);
}

__device__ __forceinline__ void split8(f32x4 va, f32x4 vb, bf16x8* hi, bf16x8* lo) {
#pragma unroll
    for (int j = 0; j < 4; ++j) {
        __bf16 h = (__bf16)va[j]; (*hi)[j] = h; (*lo)[j] = (__bf16)(va[j] - (float)h);
        __bf16 g = (__bf16)vb[j]; (*hi)[4 + j] = g; (*lo)[4 + j] = (__bf16)(vb[j] - (float)g);
    }
}

// R9: barrier-free autonomous-wave GRU. Block = 1 wave = 64 threads owning a
// 16-row batch tile END TO END: all 12 gate N-tiles (192 cols), state plane
// private to the wave, 180 steps with ZERO s_barrier. Within one wave the LDS
// pipe is FIFO, so scattered C-layout state writes are visible to the next
// step's A-layout reads; __builtin_amdgcn_wave_barrier() pins the compiler
// from reordering them (per-thread addresses differ -> it can't see the
// cross-lane aliasing). Numerics = R7 (proven): h plain bf16, weights hi/lo.
// 512 blocks (2 waves/CU). Weights: 48 B-frags = 192 VGPRs, resident under
// __launch_bounds__(64,1) (512-VGPR budget, 1 wave/SIMD).
__global__ __launch_bounds__(64, 1) void gru_wave(
        const float* __restrict__ z, const int* __restrict__ labels,
        const float* __restrict__ embed_w, const float* __restrict__ fc_w,
        const float* __restrict__ fc_b, const float* __restrict__ w_hh,
        const float* __restrict__ b_ih, const float* __restrict__ b_hh,
        const float* __restrict__ out_w, const float* __restrict__ out_b,
        float* __restrict__ out) {
    __shared__ __align__(16) __bf16 hb[16 * SB];   // single state plane
    __shared__ __align__(16) float  xs[16 * XSP];  // h0 input [z|embed]

    const int l   = threadIdx.x;   // 0..63
    const int q   = l >> 4;        // quad 0..3
    const int n16 = l & 15;
    const int bbase = blockIdx.x * 16;

    // ---- stage x = [z, embed(labels)] for 16 rows ----
    for (int c = l; c < 16 * 24; c += 64) {
        int m = c / 24, kk = (c % 24) * 4;
        f32x4 v;
        if (kk < 32) v = *(const f32x4*)(z + (size_t)(bbase + m) * 32 + kk);
        else         v = *(const f32x4*)(embed_w + labels[bbase + m] * 64 + (kk - 32));
        *(f32x4*)(xs + m * XSP + kk) = v;
    }

    // ---- persistent w_hh B-frags: 12 N-tiles x 2 k-halves, hi/lo split ----
    // tile t = g*4+c covers gate g, h-cols c*16+n16; B[k=q*8+j][n16]=w_hh[col][k]
    bf16x8 whi[12][2], wlo[12][2];
#pragma unroll
    for (int g = 0; g < 3; ++g)
#pragma unroll
        for (int c = 0; c < 4; ++c) {
            const float* pr = w_hh + (size_t)(g * 64 + c * 16 + n16) * 64;
#pragma unroll
            for (int ks = 0; ks < 2; ++ks) {
                const float* p = pr + ks * 32 + q * 8;
                split8(*(const f32x4*)p, *(const f32x4*)(p + 4),
                       &whi[g * 4 + c][ks], &wlo[g * 4 + c][ks]);
            }
        }

    // ---- output-head B-frags (cols n16<2 live, rest zero) ----
    bf16x8 obhi[2], oblo[2];
#pragma unroll
    for (int ks = 0; ks < 2; ++ks) {
        f32x4 va = {0.f, 0.f, 0.f, 0.f}, vb = {0.f, 0.f, 0.f, 0.f};
        if (n16 < 2) {
            va = *(const f32x4*)(out_w + n16 * 64 + ks * 32 + q * 8);
            vb = *(const f32x4*)(out_w + n16 * 64 + ks * 32 + q * 8 + 4);
        }
        split8(va, vb, &obhi[ks], &oblo[ks]);
    }
    const float bo = (n16 == 0) ? out_b[0] : (n16 == 1) ? out_b[1] : 0.f;
    const f32x4 obias = {bo, bo, bo, bo};
    const f32x4 kZ = {0.f, 0.f, 0.f, 0.f};

    // ---- per-lane, per-col-tile gate constants ----
    float cRv[4], cZv[4], bnv[4], cNv[4];
#pragma unroll
    for (int c = 0; c < 4; ++c) {
        int jc = c * 16 + n16;
        cRv[c] = -L2E * (b_ih[jc] + b_hh[jc]);
        cZv[c] = -L2E * (b_ih[64 + jc] + b_hh[64 + jc]);
        bnv[c] = b_hh[128 + jc];
        cNv[c] = 2.0f * L2E * b_ih[128 + jc];
    }

    __syncthreads();   // single wave: ~free; orders xs staging

    // ---- h0 = tanh(x @ fc_w^T + fc_b) via MFMA (x hi/lo, fc_w hi/lo, 3-term) ----
    bf16x8 xhi[3], xlo[3];
#pragma unroll
    for (int kc = 0; kc < 3; ++kc) {
        const float* p = xs + n16 * XSP + kc * 32 + q * 8;
        split8(*(const f32x4*)p, *(const f32x4*)(p + 4), &xhi[kc], &xlo[kc]);
    }
    float hprev[4][4];   // [col-tile c][row r]: (row q*4+r, col c*16+n16)
#pragma unroll
    for (int c = 0; c < 4; ++c) {
        f32x4 a = kZ;
#pragma unroll
        for (int kc = 0; kc < 3; ++kc) {
            const float* p = fc_w + (size_t)(c * 16 + n16) * 96 + kc * 32 + q * 8;
            bf16x8 fhi, flo;
            split8(*(const f32x4*)p, *(const f32x4*)(p + 4), &fhi, &flo);
            a = MFMA(xhi[kc], fhi, a, 0, 0, 0);
            a = MFMA(xlo[kc], fhi, a, 0, 0, 0);
            a = MFMA(xhi[kc], flo, a, 0, 0, 0);
        }
        float bcol = fc_b[c * 16 + n16];
#pragma unroll
        for (int r = 0; r < 4; ++r) {
            float h = tanh_f(a[r] + bcol);
            hprev[c][r] = h;
            hb[(q * 4 + r) * SB + c * 16 + n16] = (__bf16)h;
        }
    }
    __builtin_amdgcn_wave_barrier();   // writes above visible to reads below

    const int rdoff = n16 * SB + q * 8;
    float* ob = out + (size_t)(bbase + 4 * q) * (SEQ * 2) + n16;

    for (int i = 0; i < SEQ; ++i) {
        // A-frags of state H_i: A[m=n16][k=q*8+j], two k-halves
        bf16x8 a0 = *(const bf16x8*)(hb + rdoff);
        bf16x8 a1 = *(const bf16x8*)(hb + rdoff + 32);

        // output row i-1 (= H_i . out_w^T + out_b)
        if (i) {
            f32x4 o = obias;
            o = MFMA(a0, obhi[0], o, 0, 0, 0);
            o = MFMA(a1, obhi[1], o, 0, 0, 0);
            o = MFMA(a0, oblo[0], o, 0, 0, 0);
            o = MFMA(a1, oblo[1], o, 0, 0, 0);
            if (n16 < 2) {
#pragma unroll
                for (int r = 0; r < 4; ++r)
                    ob[r * (SEQ * 2) + (i - 1) * 2] = o[r];
            }
        }

        // gates: 12 independent 4-deep chains (breadth-first issue)
        f32x4 acc[12];
#pragma unroll
        for (int t = 0; t < 12; ++t) acc[t] = MFMA(a0, whi[t][0], kZ, 0, 0, 0);
#pragma unroll
        for (int t = 0; t < 12; ++t) acc[t] = MFMA(a1, whi[t][1], acc[t], 0, 0, 0);
#pragma unroll
        for (int t = 0; t < 12; ++t) acc[t] = MFMA(a0, wlo[t][0], acc[t], 0, 0, 0);
#pragma unroll
        for (int t = 0; t < 12; ++t) acc[t] = MFMA(a1, wlo[t][1], acc[t], 0, 0, 0);

        // epilogue: 16 h-updates (4 col-tiles x 4 rows), fp32 carry exact
#pragma unroll
        for (int c = 0; c < 4; ++c) {
            f32x4 aR = acc[c], aZ = acc[4 + c], aN = acc[8 + c];
#pragma unroll
            for (int r = 0; r < 4; ++r) {
                float eR = __builtin_amdgcn_exp2f(__builtin_fmaf(-L2E, aR[r], cRv[c]));
                float rg = __builtin_amdgcn_rcpf(eR + 1.0f);
                float eZ = __builtin_amdgcn_exp2f(__builtin_fmaf(-L2E, aZ[r], cZv[c]));
                float zg = __builtin_amdgcn_rcpf(eZ + 1.0f);
                float mm = aN[r] + bnv[c];
                float eN = __builtin_amdgcn_exp2f(__builtin_fmaf(2.0f * L2E, rg * mm, cNv[c]));
                float dd = __builtin_amdgcn_rcpf(eN + 1.0f);
                float ng = __builtin_fmaf(-2.0f, dd, 1.0f);
                float hn = __builtin_fmaf(zg, hprev[c][r] - ng, ng);
                hprev[c][r] = hn;
                hb[(q * 4 + r) * SB + c * 16 + n16] = (__bf16)hn;
            }
        }
        __builtin_amdgcn_wave_barrier();   // no compiler reorder across step edge
    }

    // final output row 179 from H_180
    {
        bf16x8 a0 = *(const bf16x8*)(hb + rdoff);
        bf16x8 a1 = *(const bf16x8*)(hb + rdoff + 32);
        f32x4 o = obias;
        o = MFMA(a0, obhi[0], o, 0, 0, 0);
        o = MFMA(a1, obhi[1], o, 0, 0, 0);
        o = MFMA(a0, oblo[0], o, 0, 0, 0);
        o = MFMA(a1, oblo[1], o, 0, 0, 0);
        if (n16 < 2) {
#pragma unroll
            for (int r = 0; r < 4; ++r)
                ob[r * (SEQ * 2) + (SEQ - 1) * 2] = o[r];
        }
    }
}

extern "C" void kernel_launch(void* const* d_in, const int* in_sizes, int n_in,
                              void* d_out, int out_size, void* d_ws, size_t ws_size,
                              hipStream_t stream) {
    (void)in_sizes; (void)n_in; (void)out_size; (void)d_ws; (void)ws_size;
    const float* z       = (const float*)d_in[0];
    const int*   labels  = (const int*)d_in[1];
    const float* embed_w = (const float*)d_in[2];
    const float* fc_w    = (const float*)d_in[3];
    const float* fc_b    = (const float*)d_in[4];
    // d_in[5] = w_ih: unused (GRU input is all zeros; b_ih carries the effect)
    const float* w_hh    = (const float*)d_in[6];
    const float* b_ih    = (const float*)d_in[7];
    const float* b_hh    = (const float*)d_in[8];
    const float* out_w   = (const float*)d_in[9];
    const float* out_b   = (const float*)d_in[10];
    float* out = (float*)d_out;

    gru_wave<<<NB / 16, 64, 0, stream>>>(z, labels, embed_w, fc_w, fc_b,
                                         w_hh, b_ih, b_hh, out_w, out_b, out);
}

// Round 10
// 198.779 us; speedup vs baseline: 1.5683x; 1.5683x over previous
//
#include <hip/hip_runtime.h>

#define NB     8192
#define HDIM   64
#define SEQ    180
#define MT     16     // batch rows per block
#define SB     72     // bf16 LDS row stride: 144 B, 16B-aligned (SB=68 regressed: misaligned b128)
#define XSP    100    // xs prologue row stride (floats)

typedef __bf16 bf16x8 __attribute__((ext_vector_type(8)));
typedef float  f32x4  __attribute__((ext_vector_type(4)));

#define L2E 1.44269504088896340736f

__device__ __forceinline__ float tanh_f(float x) {
    float e = __builtin_amdgcn_exp2f((2.0f * L2E) * x);
    return 1.0f - 2.0f * __builtin_amdgcn_rcpf(1.0f + e);
}

#define MFMA __builtin_amdgcn_mfma_f32_16x16x32_bf16

// R10 = R7 (141us proven: 4 waves/block, 16 rows, 512 blocks = 2/CU, one
// barrier/step, h plain bf16 + w_hh hi/lo) + two changes:
//  (1) co-resident blocks (i, i+256) phase-staggered by a one-time s_sleep so
//      each SIMD's two waves anti-phase their compute/stall intervals;
//  (2) epilogue non-trans math in f32x4 vector ops -> v_pk_*_f32 packed issue.
__global__ __launch_bounds__(256) void gru_all(
        const float* __restrict__ z, const int* __restrict__ labels,
        const float* __restrict__ embed_w, const float* __restrict__ fc_w,
        const float* __restrict__ fc_b, const float* __restrict__ w_hh,
        const float* __restrict__ b_ih, const float* __restrict__ b_hh,
        const float* __restrict__ out_w, const float* __restrict__ out_b,
        float* __restrict__ out) {
    __shared__ __align__(16) __bf16 hbuf[2][MT * SB];  // [buf] bf16(h)
    __shared__ __align__(16) float  xs[MT * XSP];      // h0 input [z|embed]

    const int t = threadIdx.x;
    const int w = t >> 6;          // wave 0..3
    const int l = t & 63;
    const int q = l >> 4;          // quad 0..3
    const int n16 = l & 15;
    const int jg = 16 * w + n16;   // gate column this lane owns
    const int bbase = blockIdx.x * MT;

    // ---- prologue A: stage x = [z, embed(labels)] for 16 rows into LDS ----
    for (int c = t; c < MT * 24; c += 256) {    // 24 f32x4 chunks per row
        int m = c / 24, kk = (c % 24) * 4;
        f32x4 v;
        if (kk < 32) v = *(const f32x4*)(z + (size_t)(bbase + m) * 32 + kk);
        else         v = *(const f32x4*)(embed_w + labels[bbase + m] * 64 + (kk - 32));
        *(f32x4*)(xs + m * XSP + kk) = v;
    }

    // ---- persistent w_hh fragments (hi/lo split -> w is fp32-exact) ----
    bf16x8 whi[3][2], wlo[3][2];
#pragma unroll
    for (int g = 0; g < 3; ++g) {
        const float* pr = w_hh + (g * 64 + jg) * HDIM;
#pragma unroll
        for (int ks = 0; ks < 2; ++ks) {
            const float* p = pr + ks * 32 + q * 8;
            f32x4 va = *(const f32x4*)(p);
            f32x4 vb = *(const f32x4*)(p + 4);
#pragma unroll
            for (int j2 = 0; j2 < 4; ++j2) {
                __bf16 hiA = (__bf16)va[j2];
                whi[g][ks][j2] = hiA;
                wlo[g][ks][j2] = (__bf16)(va[j2] - (float)hiA);
                __bf16 hiB = (__bf16)vb[j2];
                whi[g][ks][4 + j2] = hiB;
                wlo[g][ks][4 + j2] = (__bf16)(vb[j2] - (float)hiB);
            }
        }
    }

    // ---- output-head B fragments: B[k][n] = out_w[n][k] for n<2 else 0 ----
    bf16x8 obhi[2], oblo[2];
#pragma unroll
    for (int ks = 0; ks < 2; ++ks) {
        f32x4 va = {0.f, 0.f, 0.f, 0.f}, vb = {0.f, 0.f, 0.f, 0.f};
        if (n16 < 2) {
            va = *(const f32x4*)(out_w + n16 * 64 + ks * 32 + q * 8);
            vb = *(const f32x4*)(out_w + n16 * 64 + ks * 32 + q * 8 + 4);
        }
#pragma unroll
        for (int j2 = 0; j2 < 4; ++j2) {
            __bf16 hiA = (__bf16)va[j2];
            obhi[ks][j2] = hiA;
            oblo[ks][j2] = (__bf16)(va[j2] - (float)hiA);
            __bf16 hiB = (__bf16)vb[j2];
            obhi[ks][4 + j2] = hiB;
            oblo[ks][4 + j2] = (__bf16)(vb[j2] - (float)hiB);
        }
    }
    const float bo = (n16 == 0) ? out_b[0] : (n16 == 1) ? out_b[1] : 0.f;
    const f32x4 obias = {bo, bo, bo, bo};
    const f32x4 kZ = {0.f, 0.f, 0.f, 0.f};
    const f32x4 one4 = {1.f, 1.f, 1.f, 1.f};

    // per-lane gate constants (splatted for packed epilogue math)
    const float cR = -L2E * (b_ih[jg] + b_hh[jg]);
    const float cZ = -L2E * (b_ih[64 + jg] + b_hh[64 + jg]);
    const float bn = b_hh[128 + jg];
    const float cN = 2.0f * L2E * b_ih[128 + jg];
    const f32x4 cR4 = {cR, cR, cR, cR};
    const f32x4 cZ4 = {cZ, cZ, cZ, cZ};
    const f32x4 bn4 = {bn, bn, bn, bn};
    const f32x4 cN4 = {cN, cN, cN, cN};

    const int rdoff = n16 * SB + q * 8;    // A-frag element offset (16B-aligned)
    const int wroff = (4 * q) * SB + jg;   // state-write element offset
    float* oph = out + (size_t)(bbase + 4 * q) * (SEQ * 2) + n16;

    __syncthreads();   // xs ready

    // ---- prologue B: h0 = tanh(fc_b + fc_w . x); each lane -> its 4 rows ----
    f32x4 hprev;
    {
        float a[4];
#pragma unroll
        for (int r = 0; r < 4; ++r) a[r] = fc_b[jg];
        const float* wr = fc_w + jg * 96;
        for (int kc = 0; kc < 24; ++kc) {
            f32x4 wv = *(const f32x4*)(wr + kc * 4);
#pragma unroll
            for (int r = 0; r < 4; ++r) {
                f32x4 xv = *(const f32x4*)(xs + (4 * q + r) * XSP + kc * 4);
                a[r] += wv[0] * xv[0] + wv[1] * xv[1] + wv[2] * xv[2] + wv[3] * xv[3];
            }
        }
#pragma unroll
        for (int r = 0; r < 4; ++r) {
            float h = tanh_f(a[r]);
            hprev[r] = h;
            hbuf[0][wroff + r * SB] = (__bf16)h;
        }
    }
    __syncthreads();   // state 0 published in buf 0

    // Anti-phase the two co-resident blocks (i and i+256 share a CU under
    // round-robin dispatch): one-time ~512-cycle offset = half a step period,
    // so each SIMD's two waves compute while the other stalls.
    if ((blockIdx.x >> 8) & 1) __builtin_amdgcn_s_sleep(8);

    for (int u = 0; u < SEQ / 4; ++u) {
#pragma unroll
        for (int s = 0; s < 4; ++s) {
            const int p = s & 1;
            const __bf16* Hh = hbuf[p];
            __bf16* Nh = hbuf[1 - p];

            // A-frags of state i = 4u+s: A[m=n16][k=q*8+j], two k-halves
            bf16x8 ahi0 = *(const bf16x8*)(Hh + rdoff);
            bf16x8 ahi1 = *(const bf16x8*)(Hh + rdoff + 32);

            // output row i-1 (state i) on static duty wave (s+3)&3
            if ((u | s) != 0 && w == ((s + 3) & 3)) {
                f32x4 o = obias;
                o = MFMA(ahi0, obhi[0], o, 0, 0, 0);
                o = MFMA(ahi1, obhi[1], o, 0, 0, 0);
                o = MFMA(ahi0, oblo[0], o, 0, 0, 0);
                o = MFMA(ahi1, oblo[1], o, 0, 0, 0);
                if (n16 < 2) {
#pragma unroll
                    for (int r = 0; r < 4; ++r)
                        oph[r * (SEQ * 2) + 2 * s - 2] = o[r];
                }
            }

            // gates: 4-deep chain per gate (h_bf16 x [whi + wlo])
            f32x4 aR, aZ, aN;
            aR = MFMA(ahi0, whi[0][0], kZ, 0, 0, 0);
            aZ = MFMA(ahi0, whi[1][0], kZ, 0, 0, 0);
            aN = MFMA(ahi0, whi[2][0], kZ, 0, 0, 0);
            aR = MFMA(ahi1, whi[0][1], aR, 0, 0, 0);
            aZ = MFMA(ahi1, whi[1][1], aZ, 0, 0, 0);
            aN = MFMA(ahi1, whi[2][1], aN, 0, 0, 0);
            aR = MFMA(ahi0, wlo[0][0], aR, 0, 0, 0);
            aZ = MFMA(ahi0, wlo[1][0], aZ, 0, 0, 0);
            aN = MFMA(ahi0, wlo[2][0], aN, 0, 0, 0);
            aR = MFMA(ahi1, wlo[0][1], aR, 0, 0, 0);
            aZ = MFMA(ahi1, wlo[1][1], aZ, 0, 0, 0);
            aN = MFMA(ahi1, wlo[2][1], aN, 0, 0, 0);

            // epilogue: non-trans math as f32x4 vector ops (-> v_pk_*_f32),
            // trans (exp2/rcp) scalar per element. Same numerics as R7.
            f32x4 tR = aR * (-L2E) + cR4;
            f32x4 tZ = aZ * (-L2E) + cZ4;
            f32x4 eR, eZ;
#pragma unroll
            for (int r = 0; r < 4; ++r) {
                eR[r] = __builtin_amdgcn_exp2f(tR[r]);
                eZ[r] = __builtin_amdgcn_exp2f(tZ[r]);
            }
            eR = eR + one4;
            eZ = eZ + one4;
            f32x4 rg, zg;
#pragma unroll
            for (int r = 0; r < 4; ++r) {
                rg[r] = __builtin_amdgcn_rcpf(eR[r]);
                zg[r] = __builtin_amdgcn_rcpf(eZ[r]);
            }
            f32x4 mm = aN + bn4;
            f32x4 tN = (rg * mm) * (2.0f * L2E) + cN4;
            f32x4 eN;
#pragma unroll
            for (int r = 0; r < 4; ++r) eN[r] = __builtin_amdgcn_exp2f(tN[r]);
            eN = eN + one4;
            f32x4 dd;
#pragma unroll
            for (int r = 0; r < 4; ++r) dd[r] = __builtin_amdgcn_rcpf(eN[r]);
            f32x4 ng = dd * (-2.0f) + one4;
            f32x4 hn = zg * (hprev - ng) + ng;   // exact fp32 carry
            hprev = hn;
#pragma unroll
            for (int r = 0; r < 4; ++r)
                Nh[wroff + r * SB] = (__bf16)hn[r];

            __syncthreads();   // state i+1 published
        }
        oph += 8;   // 4 steps x 2 output cols
    }

    // final output: row 179 (state 180, in buf 0), duty wave 3
    if (w == 3) {
        const __bf16* Hh = hbuf[0];
        bf16x8 ahi0 = *(const bf16x8*)(Hh + rdoff);
        bf16x8 ahi1 = *(const bf16x8*)(Hh + rdoff + 32);
        f32x4 o = obias;
        o = MFMA(ahi0, obhi[0], o, 0, 0, 0);
        o = MFMA(ahi1, obhi[1], o, 0, 0, 0);
        o = MFMA(ahi0, oblo[0], o, 0, 0, 0);
        o = MFMA(ahi1, oblo[1], o, 0, 0, 0);
        if (n16 < 2) {
#pragma unroll
            for (int r = 0; r < 4; ++r)
                oph[r * (SEQ * 2) - 2] = o[r];
        }
    }
}

extern "C" void kernel_launch(void* const* d_in, const int* in_sizes, int n_in,
                              void* d_out, int out_size, void* d_ws, size_t ws_size,
                              hipStream_t stream) {
    (void)in_sizes; (void)n_in; (void)out_size; (void)d_ws; (void)ws_size;
    const float* z       = (const float*)d_in[0];
    const int*   labels  = (const int*)d_in[1];
    const float* embed_w = (const float*)d_in[2];
    const float* fc_w    = (const float*)d_in[3];
    const float* fc_b    = (const float*)d_in[4];
    // d_in[5] = w_ih: unused (GRU input is all zeros; b_ih carries the effect)
    const float* w_hh    = (const float*)d_in[6];
    const float* b_ih    = (const float*)d_in[7];
    const float* b_hh    = (const float*)d_in[8];
    const float* out_w   = (const float*)d_in[9];
    const float* out_b   = (const float*)d_in[10];
    float* out = (float*)d_out;

    gru_all<<<NB / MT, 256, 0, stream>>>(z, labels, embed_w, fc_w, fc_b,
                                         w_hh, b_ih, b_hh, out_w, out_b, out);
}

// Round 11
// 180.899 us; speedup vs baseline: 1.7233x; 1.0988x over previous
//
#include <hip/hip_runtime.h>

#define NB     8192
#define HDIM   64
#define SEQ    180
#define MT     16     // batch rows per block
#define SB     72     // bf16 LDS row stride: 144 B, 16B-aligned (SB=68 regressed: misaligned b128)
#define XSP    100    // xs prologue row stride (floats)

typedef __bf16 bf16x8 __attribute__((ext_vector_type(8)));
typedef float  f32x4  __attribute__((ext_vector_type(4)));

#define L2E 1.44269504088896340736f

__device__ __forceinline__ float tanh_f(float x) {
    float e = __builtin_amdgcn_exp2f((2.0f * L2E) * x);
    return 1.0f - 2.0f * __builtin_amdgcn_rcpf(1.0f + e);
}

#define MFMA __builtin_amdgcn_mfma_f32_16x16x32_bf16

// R11 = R10 minus the weight hi/lo split: W enters MFMA as plain bf16.
// Rationale: per-SIMD matrix pipe was ~504 cyc/period (13 MFMA/wave-step x
// 19.4 cyc), co-equal with VALU; absmax has been frozen at 2^-9 through all
// previous numerics changes, so the W-rounding headroom is untested but the
// threshold (1.19e-2) has 6x margin. 6 gate-MFMA + 2 out-MFMA per wave-step.
// Keeps: 4 waves/block, 16 rows, 512 blocks (2/CU), one barrier/step, fp32
// carry in registers, packed f32x4 epilogue, co-resident block phase stagger.
__global__ __launch_bounds__(256) void gru_all(
        const float* __restrict__ z, const int* __restrict__ labels,
        const float* __restrict__ embed_w, const float* __restrict__ fc_w,
        const float* __restrict__ fc_b, const float* __restrict__ w_hh,
        const float* __restrict__ b_ih, const float* __restrict__ b_hh,
        const float* __restrict__ out_w, const float* __restrict__ out_b,
        float* __restrict__ out) {
    __shared__ __align__(16) __bf16 hbuf[2][MT * SB];  // [buf] bf16(h)
    __shared__ __align__(16) float  xs[MT * XSP];      // h0 input [z|embed]

    const int t = threadIdx.x;
    const int w = t >> 6;          // wave 0..3
    const int l = t & 63;
    const int q = l >> 4;          // quad 0..3
    const int n16 = l & 15;
    const int jg = 16 * w + n16;   // gate column this lane owns
    const int bbase = blockIdx.x * MT;

    // ---- prologue A: stage x = [z, embed(labels)] for 16 rows into LDS ----
    for (int c = t; c < MT * 24; c += 256) {    // 24 f32x4 chunks per row
        int m = c / 24, kk = (c % 24) * 4;
        f32x4 v;
        if (kk < 32) v = *(const f32x4*)(z + (size_t)(bbase + m) * 32 + kk);
        else         v = *(const f32x4*)(embed_w + labels[bbase + m] * 64 + (kk - 32));
        *(f32x4*)(xs + m * XSP + kk) = v;
    }

    // ---- persistent w_hh fragments, plain bf16 (R11: wlo dropped) ----
    // B-frag for mfma_f32_16x16x32_bf16: B[k = q*8+j][n16]; value w_hh[jg_g][k]
    bf16x8 whi[3][2];
#pragma unroll
    for (int g = 0; g < 3; ++g) {
        const float* pr = w_hh + (g * 64 + jg) * HDIM;
#pragma unroll
        for (int ks = 0; ks < 2; ++ks) {
            const float* p = pr + ks * 32 + q * 8;
            f32x4 va = *(const f32x4*)(p);
            f32x4 vb = *(const f32x4*)(p + 4);
#pragma unroll
            for (int j2 = 0; j2 < 4; ++j2) {
                whi[g][ks][j2]     = (__bf16)va[j2];
                whi[g][ks][4 + j2] = (__bf16)vb[j2];
            }
        }
    }

    // ---- output-head B fragments, plain bf16: B[k][n]=out_w[n][k], n<2 ----
    bf16x8 obhi[2];
#pragma unroll
    for (int ks = 0; ks < 2; ++ks) {
        f32x4 va = {0.f, 0.f, 0.f, 0.f}, vb = {0.f, 0.f, 0.f, 0.f};
        if (n16 < 2) {
            va = *(const f32x4*)(out_w + n16 * 64 + ks * 32 + q * 8);
            vb = *(const f32x4*)(out_w + n16 * 64 + ks * 32 + q * 8 + 4);
        }
#pragma unroll
        for (int j2 = 0; j2 < 4; ++j2) {
            obhi[ks][j2]     = (__bf16)va[j2];
            obhi[ks][4 + j2] = (__bf16)vb[j2];
        }
    }
    const float bo = (n16 == 0) ? out_b[0] : (n16 == 1) ? out_b[1] : 0.f;
    const f32x4 obias = {bo, bo, bo, bo};
    const f32x4 kZ = {0.f, 0.f, 0.f, 0.f};
    const f32x4 one4 = {1.f, 1.f, 1.f, 1.f};

    // per-lane gate constants (splatted for packed epilogue math)
    const float cR = -L2E * (b_ih[jg] + b_hh[jg]);
    const float cZ = -L2E * (b_ih[64 + jg] + b_hh[64 + jg]);
    const float bn = b_hh[128 + jg];
    const float cN = 2.0f * L2E * b_ih[128 + jg];
    const f32x4 cR4 = {cR, cR, cR, cR};
    const f32x4 cZ4 = {cZ, cZ, cZ, cZ};
    const f32x4 bn4 = {bn, bn, bn, bn};
    const f32x4 cN4 = {cN, cN, cN, cN};

    const int rdoff = n16 * SB + q * 8;    // A-frag element offset (16B-aligned)
    const int wroff = (4 * q) * SB + jg;   // state-write element offset
    float* oph = out + (size_t)(bbase + 4 * q) * (SEQ * 2) + n16;

    __syncthreads();   // xs ready

    // ---- prologue B: h0 = tanh(fc_b + fc_w . x); each lane -> its 4 rows ----
    f32x4 hprev;
    {
        float a[4];
#pragma unroll
        for (int r = 0; r < 4; ++r) a[r] = fc_b[jg];
        const float* wr = fc_w + jg * 96;
        for (int kc = 0; kc < 24; ++kc) {
            f32x4 wv = *(const f32x4*)(wr + kc * 4);
#pragma unroll
            for (int r = 0; r < 4; ++r) {
                f32x4 xv = *(const f32x4*)(xs + (4 * q + r) * XSP + kc * 4);
                a[r] += wv[0] * xv[0] + wv[1] * xv[1] + wv[2] * xv[2] + wv[3] * xv[3];
            }
        }
#pragma unroll
        for (int r = 0; r < 4; ++r) {
            float h = tanh_f(a[r]);
            hprev[r] = h;
            hbuf[0][wroff + r * SB] = (__bf16)h;
        }
    }
    __syncthreads();   // state 0 published in buf 0

    // Anti-phase the two co-resident blocks (i and i+256 share a CU under
    // round-robin dispatch): one-time offset ~ half a step period.
    if ((blockIdx.x >> 8) & 1) __builtin_amdgcn_s_sleep(8);

    for (int u = 0; u < SEQ / 4; ++u) {
#pragma unroll
        for (int s = 0; s < 4; ++s) {
            const int p = s & 1;
            const __bf16* Hh = hbuf[p];
            __bf16* Nh = hbuf[1 - p];

            // A-frags of state i = 4u+s: A[m=n16][k=q*8+j], two k-halves
            bf16x8 ahi0 = *(const bf16x8*)(Hh + rdoff);
            bf16x8 ahi1 = *(const bf16x8*)(Hh + rdoff + 32);

            // output row i-1 (state i) on static duty wave (s+3)&3
            if ((u | s) != 0 && w == ((s + 3) & 3)) {
                f32x4 o = obias;
                o = MFMA(ahi0, obhi[0], o, 0, 0, 0);
                o = MFMA(ahi1, obhi[1], o, 0, 0, 0);
                if (n16 < 2) {
#pragma unroll
                    for (int r = 0; r < 4; ++r)
                        oph[r * (SEQ * 2) + 2 * s - 2] = o[r];
                }
            }

            // gates: 2-deep chain per gate, plain-bf16 weights
            f32x4 aR, aZ, aN;
            aR = MFMA(ahi0, whi[0][0], kZ, 0, 0, 0);
            aZ = MFMA(ahi0, whi[1][0], kZ, 0, 0, 0);
            aN = MFMA(ahi0, whi[2][0], kZ, 0, 0, 0);
            aR = MFMA(ahi1, whi[0][1], aR, 0, 0, 0);
            aZ = MFMA(ahi1, whi[1][1], aZ, 0, 0, 0);
            aN = MFMA(ahi1, whi[2][1], aN, 0, 0, 0);

            // epilogue: non-trans math as f32x4 vector ops (-> v_pk_*_f32),
            // trans (exp2/rcp) scalar per element.
            f32x4 tR = aR * (-L2E) + cR4;
            f32x4 tZ = aZ * (-L2E) + cZ4;
            f32x4 eR, eZ;
#pragma unroll
            for (int r = 0; r < 4; ++r) {
                eR[r] = __builtin_amdgcn_exp2f(tR[r]);
                eZ[r] = __builtin_amdgcn_exp2f(tZ[r]);
            }
            eR = eR + one4;
            eZ = eZ + one4;
            f32x4 rg, zg;
#pragma unroll
            for (int r = 0; r < 4; ++r) {
                rg[r] = __builtin_amdgcn_rcpf(eR[r]);
                zg[r] = __builtin_amdgcn_rcpf(eZ[r]);
            }
            f32x4 mm = aN + bn4;
            f32x4 tN = (rg * mm) * (2.0f * L2E) + cN4;
            f32x4 eN;
#pragma unroll
            for (int r = 0; r < 4; ++r) eN[r] = __builtin_amdgcn_exp2f(tN[r]);
            eN = eN + one4;
            f32x4 dd;
#pragma unroll
            for (int r = 0; r < 4; ++r) dd[r] = __builtin_amdgcn_rcpf(eN[r]);
            f32x4 ng = dd * (-2.0f) + one4;
            f32x4 hn = zg * (hprev - ng) + ng;   // exact fp32 carry
            hprev = hn;
#pragma unroll
            for (int r = 0; r < 4; ++r)
                Nh[wroff + r * SB] = (__bf16)hn[r];

            __syncthreads();   // state i+1 published
        }
        oph += 8;   // 4 steps x 2 output cols
    }

    // final output: row 179 (state 180, in buf 0), duty wave 3
    if (w == 3) {
        const __bf16* Hh = hbuf[0];
        bf16x8 ahi0 = *(const bf16x8*)(Hh + rdoff);
        bf16x8 ahi1 = *(const bf16x8*)(Hh + rdoff + 32);
        f32x4 o = obias;
        o = MFMA(ahi0, obhi[0], o, 0, 0, 0);
        o = MFMA(ahi1, obhi[1], o, 0, 0, 0);
        if (n16 < 2) {
#pragma unroll
            for (int r = 0; r < 4; ++r)
                oph[r * (SEQ * 2) - 2] = o[r];
        }
    }
}

extern "C" void kernel_launch(void* const* d_in, const int* in_sizes, int n_in,
                              void* d_out, int out_size, void* d_ws, size_t ws_size,
                              hipStream_t stream) {
    (void)in_sizes; (void)n_in; (void)out_size; (void)d_ws; (void)ws_size;
    const float* z       = (const float*)d_in[0];
    const int*   labels  = (const int*)d_in[1];
    const float* embed_w = (const float*)d_in[2];
    const float* fc_w    = (const float*)d_in[3];
    const float* fc_b    = (const float*)d_in[4];
    // d_in[5] = w_ih: unused (GRU input is all zeros; b_ih carries the effect)
    const float* w_hh    = (const float*)d_in[6];
    const float* b_ih    = (const float*)d_in[7];
    const float* b_hh    = (const float*)d_in[8];
    const float* out_w   = (const float*)d_in[9];
    const float* out_b   = (const float*)d_in[10];
    float* out = (float*)d_out;

    gru_all<<<NB / MT, 256, 0, stream>>>(z, labels, embed_w, fc_w, fc_b,
                                         w_hh, b_ih, b_hh, out_w, out_b, out);
}